// Round 1
// 1109.422 us; speedup vs baseline: 1.0042x; 1.0042x over previous
//
#include <hip/hip_runtime.h>
#include <hip/hip_bf16.h>
#include <cstdint>
#include <cstddef>

// ---------------------------------------------------------------------------
// EnrichAttention: B=32, L1=L2=512, H=A=256, 3H=768, 2H=512
// R7: GRU matvec hp = whh*h moved from per-thread f16 dot2 (384 broadcast
//     ds_read_b128/CU/step) to MFMA f16 with register-resident weights
//     (64 ds_read_b128/CU/step). Gate phase widened to 256 threads.
//     GEMM/MFMA GEMM pipeline identical to the passing R6.
// ---------------------------------------------------------------------------

typedef short s8v __attribute__((ext_vector_type(8)));      // 8 bf16 (4 VGPRs)
typedef float f4v __attribute__((ext_vector_type(4)));      // MFMA accumulator
typedef _Float16 h8v __attribute__((ext_vector_type(8)));   // 8 f16 (4 VGPRs)

#if __has_builtin(__builtin_amdgcn_sched_barrier)
#define SCHED_FENCE() __builtin_amdgcn_sched_barrier(0)
#else
#define SCHED_FENCE() asm volatile("" ::: "memory")
#endif

// Workgroup barrier waiting only on LDS (lgkmcnt). Only hhf/hp (LDS) carry
// cross-thread deps in the GRU loop. (Validated in R2/R5.)
__device__ __forceinline__ void bar_lds() {
    asm volatile("s_waitcnt lgkmcnt(0)\n\ts_barrier" ::: "memory");
}

__device__ __forceinline__ float fast_exp(float x) {
#if __has_builtin(__builtin_amdgcn_exp2f)
    return __builtin_amdgcn_exp2f(x * 1.44269504f);
#else
    return __expf(x);
#endif
}
__device__ __forceinline__ float fast_rcp(float x) {
#if __has_builtin(__builtin_amdgcn_rcpf)
    return __builtin_amdgcn_rcpf(x);
#else
    return 1.f / x;
#endif
}
__device__ __forceinline__ float fast_sig(float x) { return fast_rcp(1.f + fast_exp(-x)); }
__device__ __forceinline__ float fast_tanh(float x) {
    return 1.f - 2.f * fast_rcp(1.f + fast_exp(2.f * x));
}

// ---------------------------------------------------------------------------
// MFMA bf16 NT GEMM: C[M,N] = A[M,K] * B[N,K]^T, A/B bf16, C fp32 or bf16.
// 128x128 block, 4 waves (2x2 of 64x64), BK=32. (Verified in R5.)
// ---------------------------------------------------------------------------
__global__ __launch_bounds__(256) void gemm_bf16(
    const __hip_bfloat16* __restrict__ A, int lda, long long sA,
    const __hip_bfloat16* __restrict__ B, int ldb, long long sB,
    void* __restrict__ C, int ldc, long long sC,
    int K,
    const float* __restrict__ bias,
    const float* __restrict__ emul, int ldmul,
    int relu, int accum, int out_bf16)
{
    __shared__ short As[128][40];
    __shared__ short Bs[128][40];

    const int tid  = threadIdx.x;
    const int wave = tid >> 6, lane = tid & 63;
    const int quad = lane >> 4, l16 = lane & 15;
    const int wrow = (wave >> 1) * 64, wcol = (wave & 1) * 64;
    const int m0 = blockIdx.y * 128, n0 = blockIdx.x * 128;

    const short* Ab = (const short*)A + (size_t)blockIdx.z * sA;
    const short* Bb = (const short*)B + (size_t)blockIdx.z * sB;

    f4v acc[4][4];
#pragma unroll
    for (int i = 0; i < 4; ++i)
#pragma unroll
        for (int j = 0; j < 4; ++j) acc[i][j] = 0.f;

    const int r0 = tid >> 2,        s0 = (tid & 3) * 8;
    const int r1 = (tid + 256) >> 2, s1 = ((tid + 256) & 3) * 8;

    for (int k0 = 0; k0 < K; k0 += 32) {
        *(s8v*)&As[r0][s0] = *(const s8v*)(Ab + (size_t)(m0 + r0) * lda + k0 + s0);
        *(s8v*)&As[r1][s1] = *(const s8v*)(Ab + (size_t)(m0 + r1) * lda + k0 + s1);
        *(s8v*)&Bs[r0][s0] = *(const s8v*)(Bb + (size_t)(n0 + r0) * ldb + k0 + s0);
        *(s8v*)&Bs[r1][s1] = *(const s8v*)(Bb + (size_t)(n0 + r1) * ldb + k0 + s1);
        __syncthreads();

        s8v af[4], bf[4];
#pragma unroll
        for (int i = 0; i < 4; ++i)
            af[i] = *(const s8v*)&As[wrow + i * 16 + l16][quad * 8];
#pragma unroll
        for (int j = 0; j < 4; ++j)
            bf[j] = *(const s8v*)&Bs[wcol + j * 16 + l16][quad * 8];
#pragma unroll
        for (int i = 0; i < 4; ++i)
#pragma unroll
            for (int j = 0; j < 4; ++j)
                acc[i][j] = __builtin_amdgcn_mfma_f32_16x16x32_bf16(
                    af[i], bf[j], acc[i][j], 0, 0, 0);
        __syncthreads();
    }

    float* Cf = (float*)C + (size_t)blockIdx.z * sC;
    __hip_bfloat16* Cb = (__hip_bfloat16*)C + (size_t)blockIdx.z * sC;
#pragma unroll
    for (int i = 0; i < 4; ++i)
#pragma unroll
        for (int j = 0; j < 4; ++j)
#pragma unroll
            for (int r = 0; r < 4; ++r) {
                const int m = m0 + wrow + i * 16 + quad * 4 + r;
                const int n = n0 + wcol + j * 16 + l16;
                float v = acc[i][j][r];
                if (bias)  v += bias[n];
                if (accum) v += Cf[(size_t)m * ldc + n];
                if (emul)  v *= emul[(size_t)m * ldmul + n];
                if (relu)  v = fmaxf(v, 0.f);
                if (out_bf16) Cb[(size_t)m * ldc + n] = __float2bfloat16(v);
                else          Cf[(size_t)m * ldc + n] = v;
            }
}

// fp32 -> bf16 elementwise (n % 4 == 0)
__global__ __launch_bounds__(256) void f2b(
    const float* __restrict__ s, __hip_bfloat16* __restrict__ d, int n)
{
    const int i = (blockIdx.x * 256 + threadIdx.x) * 4;
    if (i < n) {
        float4 v = *(const float4*)(s + i);
        d[i + 0] = __float2bfloat16(v.x);
        d[i + 1] = __float2bfloat16(v.y);
        d[i + 2] = __float2bfloat16(v.z);
        d[i + 3] = __float2bfloat16(v.w);
    }
}

// fp32 [Z][R][C] -> bf16 [Z][C][R] tiled transpose
__global__ __launch_bounds__(256) void tr_f2b(
    const float* __restrict__ src, __hip_bfloat16* __restrict__ dst,
    int R, int C, long long sS, long long sD)
{
    __shared__ float t[32][33];
    const int r0 = blockIdx.y * 32, c0 = blockIdx.x * 32;
    const int tx = threadIdx.x & 31, ty = threadIdx.x >> 5;
    const float* S = src + (size_t)blockIdx.z * sS;
    __hip_bfloat16* Dd = dst + (size_t)blockIdx.z * sD;
#pragma unroll
    for (int i = 0; i < 32; i += 8)
        t[ty + i][tx] = S[(size_t)(r0 + ty + i) * C + c0 + tx];
    __syncthreads();
#pragma unroll
    for (int i = 0; i < 32; i += 8)
        Dd[(size_t)(c0 + ty + i) * R + r0 + tx] = __float2bfloat16(t[tx][ty + i]);
}

// softmax over axis=1 (i) for each (b, j): fp32 in, bf16 out
__global__ __launch_bounds__(256) void softmax_dim1(
    const float* __restrict__ Mf, __hip_bfloat16* __restrict__ Ms)
{
    const int j = blockIdx.x * 256 + threadIdx.x;
    const float* base = Mf + (size_t)blockIdx.y * 262144;
    __hip_bfloat16* ob = Ms + (size_t)blockIdx.y * 262144;

    float mx = -1e30f;
    for (int i = 0; i < 512; ++i)
        mx = fmaxf(mx, base[(size_t)i * 512 + j]);
    float s = 0.f;
    for (int i = 0; i < 512; ++i)
        s += __expf(base[(size_t)i * 512 + j] - mx);
    const float inv = 1.f / s;
    for (int i = 0; i < 512; ++i)
        ob[(size_t)i * 512 + j] =
            __float2bfloat16(__expf(base[(size_t)i * 512 + j] - mx) * inv);
}

// ---------------------------------------------------------------------------
// GRU, R7: hp[768] = whh[768,256] @ h[256] via mfma_f32_16x16x32_f16.
//   512 threads = 8 waves; wave w owns output rows 96w..96w+95 (6 16-row
//   tiles). Weight A-fragments live in 192 VGPRs (f16). Per k-step the wave
//   reads ONE 16-byte B-fragment of h from LDS (vs 32 broadcast b128 reads
//   per THREAD in R6). Fragment mapping mirrors the verified gemm_bf16:
//     A: lane -> A[row=l16][k=quad*8+j];  B: lane -> B[n=l16][k=quad*8+j]
//     D: lane -> D[row=quad*4+r][col=l16]
//   All lanes get the same B data so every D column equals hp; column 0
//   (l16==0 lanes) is stored. Gate phase: 256 threads, 1 h-element each.
// ---------------------------------------------------------------------------
__global__ __launch_bounds__(512, 2)
void gru_kernel(
    const float* __restrict__ xproj,   // [B, T, 768]
    const float* __restrict__ whh,     // [768, 256]
    const float* __restrict__ bhh,     // [768]
    float* __restrict__ out)           // [B, T, 256]
{
    const int b    = blockIdx.x;
    const int tid  = threadIdx.x;
    const int wave = tid >> 6, lane = tid & 63;
    const int quad = lane >> 4, l16 = lane & 15;

    __shared__ __align__(16) _Float16 hhf[256];   // h (f16), B operand
    __shared__ __align__(16) float    hp[768];    // whh @ h

    // --- Preload weight A-fragments: wreg[i][kk] = whh[96w+16i+l16][kk*32+quad*8 ..+7]
    h8v wreg[6][8];
#pragma unroll
    for (int i = 0; i < 6; ++i) {
        const float* rp = whh + (size_t)(96 * wave + 16 * i + l16) * 256 + quad * 8;
#pragma unroll
        for (int kk = 0; kk < 8; ++kk) {
            float4 t0 = *(const float4*)(rp + kk * 32);
            float4 t1 = *(const float4*)(rp + kk * 32 + 4);
            h8v f;
            f[0] = (_Float16)t0.x; f[1] = (_Float16)t0.y;
            f[2] = (_Float16)t0.z; f[3] = (_Float16)t0.w;
            f[4] = (_Float16)t1.x; f[5] = (_Float16)t1.y;
            f[6] = (_Float16)t1.z; f[7] = (_Float16)t1.w;
            wreg[i][kk] = f;
        }
    }

    const float* xb = xproj + (size_t)b * 512 * 768;
    float*       ob = out   + (size_t)b * 512 * 256;

    float hA = 0.f, xr = 0.f, xz = 0.f, xn = 0.f;
    float br = 0.f, bz = 0.f, bn = 0.f;
    if (tid < 256) {
        br = bhh[tid]; bz = bhh[256 + tid]; bn = bhh[512 + tid];
        xr = xb[tid];  xz = xb[256 + tid];  xn = xb[512 + tid];
        hhf[tid] = (_Float16)0.f;
    }
    bar_lds();

    for (int t = 0; t < 512; ++t) {
        // ---- phase A: hp = whh @ h via MFMA --------------------------------
        f4v acc[6];
#pragma unroll
        for (int i = 0; i < 6; ++i) acc[i] = 0.f;

        h8v bf_cur = *(const h8v*)&hhf[quad * 8];
#pragma unroll
        for (int kk = 0; kk < 8; ++kk) {
            h8v bf_nxt = bf_cur;
            if (kk < 7) bf_nxt = *(const h8v*)&hhf[(kk + 1) * 32 + quad * 8];
#pragma unroll
            for (int i = 0; i < 6; ++i)
                acc[i] = __builtin_amdgcn_mfma_f32_16x16x32_f16(
                    wreg[i][kk], bf_cur, acc[i], 0, 0, 0);
            SCHED_FENCE();   // bound bf live range (VGPR budget), keep pipeline 1-deep
            bf_cur = bf_nxt;
        }

        if (l16 == 0) {      // lanes 0,16,32,48: rows 96w+16i+4q+{0..3}, col 0
#pragma unroll
            for (int i = 0; i < 6; ++i)
                *(f4v*)&hp[96 * wave + 16 * i + 4 * quad] = acc[i];
        }
        bar_lds();

        // ---- phase B: gates on 256 threads (1 h each) ----------------------
        if (tid < 256) {
            const int tn = (t + 1) & 511;
            const float* xpn = xb + (size_t)tn * 768;
            float nxr = xpn[tid], nxz = xpn[256 + tid], nxn = xpn[512 + tid];

            float hr = hp[tid]       + br;
            float hz = hp[256 + tid] + bz;
            float hn = hp[512 + tid] + bn;
            float r = fast_sig(xr + hr);
            float z = fast_sig(xz + hz);
            float n = fast_tanh(xn + r * hn);
            float h = (1.f - z) * n + z * hA;
            hA = h;
            hhf[tid] = (_Float16)h;
            ob[(size_t)t * 256 + tid] = h;
            xr = nxr; xz = nxz; xn = nxn;
        }
        bar_lds();
    }
}

extern "C" void kernel_launch(void* const* d_in, const int* in_sizes, int n_in,
                              void* d_out, int out_size, void* d_ws, size_t ws_size,
                              hipStream_t stream)
{
    (void)in_sizes; (void)n_in; (void)out_size; (void)ws_size;

    const float* x1  = (const float*)d_in[0];   // [32,512,256]
    const float* x2  = (const float*)d_in[1];   // [32,512,256]
    const float* w1  = (const float*)d_in[2];   // [256,256]
    const float* w2  = (const float*)d_in[3];   // [256,256]
    const float* Dm  = (const float*)d_in[4];   // [256,256]
    const float* Wm  = (const float*)d_in[5];   // [512,512]
    const float* wih = (const float*)d_in[6];   // [768,512]
    const float* whh = (const float*)d_in[7];   // [768,256]
    const float* bih = (const float*)d_in[8];   // [768]
    const float* bhh = (const float*)d_in[9];   // [768]
    float* out = (float*)d_out;

    // Workspace aliasing identical to the passing R5/R6.
    char* base = (char*)d_ws;
    __hip_bfloat16* w1b  = (__hip_bfloat16*)(base + 0);
    __hip_bfloat16* w2b  = (__hip_bfloat16*)(base + 131072);
    __hip_bfloat16* Dtb  = (__hip_bfloat16*)(base + 262144);
    float*          Mf   = (float*)(base + 0);
    float*          xp   = (float*)(base + 0);
    __hip_bfloat16* a1b  = (__hip_bfloat16*)(base + 33554432);
    __hip_bfloat16* a1db = (__hip_bfloat16*)(base + 41943040);
    __hip_bfloat16* Msb  = (__hip_bfloat16*)(base + 33554432);
    __hip_bfloat16* x1b  = (__hip_bfloat16*)(base + 50331648);
    __hip_bfloat16* x2b  = (__hip_bfloat16*)(base + 58720256);
    __hip_bfloat16* ctxb = (__hip_bfloat16*)(base + 58720256);
    __hip_bfloat16* x2tb = (__hip_bfloat16*)(base + 67108864);
    __hip_bfloat16* a2b  = (__hip_bfloat16*)(base + 75497472);
    __hip_bfloat16* wihb = (__hip_bfloat16*)(base + 75497472);

    dim3 blk(256);

    f2b<<<dim3(4096), blk, 0, stream>>>(x1, x1b, 4194304);
    f2b<<<dim3(4096), blk, 0, stream>>>(x2, x2b, 4194304);
    f2b<<<dim3(64),   blk, 0, stream>>>(w1, w1b, 65536);
    f2b<<<dim3(64),   blk, 0, stream>>>(w2, w2b, 65536);
    tr_f2b<<<dim3(8, 16, 32), blk, 0, stream>>>(x2, x2tb, 512, 256, 131072, 131072);
    tr_f2b<<<dim3(8, 8, 1),   blk, 0, stream>>>(Dm, Dtb, 256, 256, 0, 0);

    gemm_bf16<<<dim3(2, 128, 1), blk, 0, stream>>>(
        x1b, 256, 0, w1b, 256, 0, a1b, 256, 0, 256,
        nullptr, nullptr, 0, 1, 0, 1);
    gemm_bf16<<<dim3(2, 128, 1), blk, 0, stream>>>(
        x2b, 256, 0, w2b, 256, 0, a2b, 256, 0, 256,
        nullptr, nullptr, 0, 1, 0, 1);
    gemm_bf16<<<dim3(2, 128, 1), blk, 0, stream>>>(
        a1b, 256, 0, Dtb, 256, 0, a1db, 256, 0, 256,
        nullptr, nullptr, 0, 0, 0, 1);
    gemm_bf16<<<dim3(4, 4, 32), blk, 0, stream>>>(
        a1db, 256, 131072, a2b, 256, 131072, Mf, 512, 262144, 256,
        nullptr, Wm, 512, 0, 0, 0);
    f2b<<<dim3(384), blk, 0, stream>>>(wih, wihb, 393216);
    softmax_dim1<<<dim3(2, 32), blk, 0, stream>>>(Mf, Msb);
    gemm_bf16<<<dim3(2, 4, 32), blk, 0, stream>>>(
        Msb, 512, 262144, x2tb, 512, 131072, ctxb, 256, 131072, 512,
        nullptr, nullptr, 0, 0, 0, 1);
    gemm_bf16<<<dim3(6, 128, 1), blk, 0, stream>>>(
        x1b, 256, 0, wihb, 512, 0, xp, 768, 0, 256,
        bih, nullptr, 0, 0, 0, 0);
    gemm_bf16<<<dim3(6, 128, 1), blk, 0, stream>>>(
        ctxb, 256, 0, wihb + 256, 512, 0, xp, 768, 0, 256,
        nullptr, nullptr, 0, 0, 1, 0);
    gru_kernel<<<dim3(32), dim3(512), 0, stream>>>(xp, whh, bhh, out);
}